// Round 23
// baseline (221.915 us; speedup 1.0000x reference)
//
#include <hip/hip_runtime.h>
#include <hip/hip_bf16.h>

// N=1e6 nodes, V=6e5 var nodes, H=128.
constexpr int H = 128;
constexpr int V = 600000;
constexpr int NTOT = 1000000;
constexpr int NT = 60;      // tiles/compute block; 625 x 60 x 16 = 600000 exact
constexpr int NCOMP = 625;  // compute blocks (b < NCOMP)
constexpr int NCOPY = 399;  // copy blocks; 625+399 = 1024 = exactly 4/CU

typedef short bf16x8 __attribute__((ext_vector_type(8)));   // 8 bf16 = 4 VGPR
typedef float f32x4 __attribute__((ext_vector_type(4)));    // clang native vec
typedef unsigned int u32;

__device__ __forceinline__ short f2bf(float f) {  // RNE bf16
    unsigned u = __float_as_uint(f);
    u += 0x7FFF + ((u >> 16) & 1);
    return (short)(u >> 16);
}

// async global->LDS; ldsDst is WAVE-UNIFORM base, lane i lands at dst+i*sz.
// aux=2 sets the NT (non-temporal) cache-policy bit on gfx940+/gfx950:
// streaming read, no L2/L3 allocation (nf is read exactly once).
__device__ __forceinline__ void async_copy16(char* ldsDst, const float* gSrc) {
    __builtin_amdgcn_global_load_lds(
        (const __attribute__((address_space(1))) u32*)gSrc,
        (__attribute__((address_space(3))) u32*)ldsDst, 16, 0, 2);
}
__device__ __forceinline__ void async_copy4(char* ldsDst, const float* gSrc) {
    __builtin_amdgcn_global_load_lds(
        (const __attribute__((address_space(1))) u32*)gSrc,
        (__attribute__((address_space(3))) u32*)ldsDst, 4, 0, 2);
}
#define FENCE() asm volatile("" ::: "memory")

// uc[h]=u, uc[128+h]=c : logits[i][h] = vf_i . W1[:,h] + llr_i*u[h] + c[h]
// uc[256..383]=W_llr, uc[384..511]=b_llr
__global__ void precompute_uc_kernel(const float* __restrict__ W_llr,
                                     const float* __restrict__ b_llr,
                                     const float* __restrict__ W_gate,
                                     const float* __restrict__ b_gate,
                                     float* __restrict__ uc) {
    int h = threadIdx.x;  // 128 threads
    float u = 0.0f, c = 0.0f;
    for (int k = 0; k < H; ++k) {
        float w2 = W_gate[(size_t)(H + k) * H + h];
        u += W_llr[k] * w2;
        c += b_llr[k] * w2;
    }
    uc[h] = u;
    uc[H + h] = c + b_gate[h];
    uc[2 * H + h] = W_llr[h];
    uc[3 * H + h] = b_llr[h];
}

// LDS 32 KB. Prologue: W1^T bf16 (128 x 256 B, n*256+k*2) -> Bf VGPRs.
// Main loop overlay: 3 A-buffers of 8 KB (16 rows x 512 B fp32) at 0/8K/16K,
// plus 3 llr slots of 256 B at 24576+bi*256.
// A-granule involution (rule 21, round-7-verified): LDS granule g' of row r
// holds global granule g'^(r&7); every read applies the same XOR.
#define LDS_BYTES 32768
#define ABUF 8192
#define LLR_BASE 24576

__global__ __launch_bounds__(256, 4) void fused_residual_llr_kernel(
    const float* __restrict__ nf,      // [N][H]
    const float* __restrict__ llr,     // [V]
    const float* __restrict__ W_gate,  // [2H][H]
    const float* __restrict__ uc,      // [4H]
    float* __restrict__ out) {         // [N][H]
    int b = blockIdx.x;
    int tid = threadIdx.x;

    if (b >= NCOMP) {
        // ---- copy role (R22-verified): rows V..N, 4-deep guarded,
        //      NON-TEMPORAL loads+stores via clang native f32x4.
        size_t base = (size_t)V * H;
        const f32x4* src = reinterpret_cast<const f32x4*>(nf + base);
        f32x4* dst = reinterpret_cast<f32x4*>(out + base);
        const size_t n4 = ((size_t)(NTOT - V) * H) / 4;  // 12.8M float4
        size_t i0 = (size_t)(b - NCOMP) * 256 + tid;
        const size_t stride = (size_t)NCOPY * 256;       // 102144
#pragma unroll 1
        for (size_t i = i0; i < n4; i += 4 * stride) {
            f32x4 v0, v1, v2, v3;
            bool g1 = i + stride < n4, g2 = i + 2 * stride < n4,
                 g3 = i + 3 * stride < n4;
            v0 = __builtin_nontemporal_load(&src[i]);
            if (g1) v1 = __builtin_nontemporal_load(&src[i + stride]);
            if (g2) v2 = __builtin_nontemporal_load(&src[i + 2 * stride]);
            if (g3) v3 = __builtin_nontemporal_load(&src[i + 3 * stride]);
            __builtin_nontemporal_store(v0, &dst[i]);
            if (g1) __builtin_nontemporal_store(v1, &dst[i + stride]);
            if (g2) __builtin_nontemporal_store(v2, &dst[i + 2 * stride]);
            if (g3) __builtin_nontemporal_store(v3, &dst[i + 3 * stride]);
        }
        return;
    }
    int cb = b;  // compute-block index 0..624; rows [cb*960, cb*960+960)

    __shared__ __align__(16) char lds[LDS_BYTES];

    int lane = tid & 63;
    int w = tid >> 6;          // wave 0..3; wave owns cols [w*32, w*32+32)
    int l15 = lane & 15;
    int l4 = lane >> 4;

    // ---- prologue: stage W1^T bf16 (linear n*256 + k*2) ----
#pragma unroll 4
    for (int j = 0; j < 16; ++j) {  // 4096 float4 of W1
        int idx = tid + 256 * j;
        int k = idx >> 5, c4 = idx & 31;
        f32x4 wv = reinterpret_cast<const f32x4*>(W_gate)[(size_t)k * 32 + c4];
#pragma unroll
        for (int e = 0; e < 4; ++e) {
            int n = c4 * 4 + e;
            *reinterpret_cast<short*>(lds + n * 256 + k * 2) = f2bf(wv[e]);
        }
    }
    float u_r[2], c_r[2], wl_r[2], bl_r[2];
#pragma unroll
    for (int nfr = 0; nfr < 2; ++nfr) {
        int col = w * 32 + nfr * 16 + l15;
        u_r[nfr]  = uc[col];
        c_r[nfr]  = uc[128 + col];
        wl_r[nfr] = uc[256 + col];
        bl_r[nfr] = uc[384 + col];
    }
    __syncthreads();

    // B fragments, held in VGPRs for all tiles
    bf16x8 Bf[4][2];
#pragma unroll
    for (int kk = 0; kk < 4; ++kk)
#pragma unroll
        for (int nfr = 0; nfr < 2; ++nfr) {
            int n = w * 32 + nfr * 16 + l15;
            Bf[kk][nfr] = *reinterpret_cast<const bf16x8*>(
                lds + n * 256 + kk * 64 + l4 * 16);
        }
    __syncthreads();  // full drain: vmcnt=0 baseline; W region reusable

    int rowBase0 = cb * (NT * 16);

    // STAGE(tt,bi): per wave exactly 3 vmem LOADS (2x copy16 A + 1x copy4 llr)
#define STAGE(tt, bi)                                                        \
    {                                                                        \
        char* nbuf_ = lds + (bi) * ABUF;                                     \
        int rb_ = rowBase0 + (tt) * 16;                                      \
        _Pragma("unroll")                                                    \
        for (int j_ = 0; j_ < 2; ++j_) {                                     \
            int seg_ = w * 2 + j_;                                           \
            int rl_ = seg_ * 2 + (lane >> 5);                                \
            int gg_ = (lane & 31) ^ (rl_ & 7);                               \
            async_copy16(nbuf_ + seg_ * 1024,                                \
                         nf + (size_t)(rb_ + rl_) * H + gg_ * 4);            \
        }                                                                    \
        async_copy4(lds + LLR_BASE + (bi) * 256, llr + rb_ + (lane & 15));   \
    }

    STAGE(0, 0);
    FENCE();
    STAGE(1, 1);
    FENCE();

    int cur = 0;  // buffer of tile t
#pragma unroll 1
    for (int t = 0; t < NT; ++t) {
        int rowBase = rowBase0 + t * 16;

        // (C) counted wait for stage(t) ONLY (issue-order FIFO, m135).
        //     Ops newer than stage(t)'s last op at this wait:
        //       t=0:     stage(1)·3                                  ->  3
        //       t=1:     stage(2)·3 + epi(0)·8                       -> 11
        //       2<=t<NT-1: epi(t-2)·8 + stage(t+1)·3 + epi(t-1)·8    -> 19
        //       t=NT-1:  epi·8 + epi·8 (no stage(NT) exists)         -> 16
        if (t == 0)           asm volatile("s_waitcnt vmcnt(3)" ::: "memory");
        else if (t == 1)      asm volatile("s_waitcnt vmcnt(11)" ::: "memory");
        else if (t == NT - 1) asm volatile("s_waitcnt vmcnt(16)" ::: "memory");
        else                  asm volatile("s_waitcnt vmcnt(19)" ::: "memory");
        // (D) raw barrier: all waves' stage(t) visible; all waves are DONE
        //     with tile t-1's buffer (they reached here only after its F).
        __builtin_amdgcn_s_barrier();
        FENCE();

        // (A) stage t+2 into b(t+2)=b(t-1) — safe only AFTER the barrier
        if (t + 2 < NT) {
            int tgt = (cur == 0) ? 2 : cur - 1;  // (cur+2)%3
            STAGE(t + 2, tgt);
        }
        FENCE();

        // (E) MFMA from buf[cur]: fp32 ds_read (swizzled) -> bf16 -> mfma
        char* buf = lds + cur * ABUF;
        f32x4 acc[2];
        acc[0] = (f32x4){0.f, 0.f, 0.f, 0.f};
        acc[1] = (f32x4){0.f, 0.f, 0.f, 0.f};
#pragma unroll
        for (int kk = 0; kk < 4; ++kk) {
            int g0 = (l4 * 2) ^ (l15 & 7);
            const char* base = buf + l15 * 512 + kk * 128;
            f32x4 lo = *reinterpret_cast<const f32x4*>(base + (g0 << 4));
            f32x4 hi = *reinterpret_cast<const f32x4*>(base + ((g0 ^ 1) << 4));
            bf16x8 a;
            a[0] = f2bf(lo[0]); a[1] = f2bf(lo[1]);
            a[2] = f2bf(lo[2]); a[3] = f2bf(lo[3]);
            a[4] = f2bf(hi[0]); a[5] = f2bf(hi[1]);
            a[6] = f2bf(hi[2]); a[7] = f2bf(hi[3]);
            acc[0] = __builtin_amdgcn_mfma_f32_16x16x32_bf16(
                a, Bf[kk][0], acc[0], 0, 0, 0);
            acc[1] = __builtin_amdgcn_mfma_f32_16x16x32_bf16(
                a, Bf[kk][1], acc[1], 0, 0, 0);
        }

        // (F) epilogue: gate, blend with exact fp32 vf from LDS, 8 stores
        //     (NON-TEMPORAL: output is write-once streaming).
        const float* llrs = reinterpret_cast<const float*>(lds + LLR_BASE + cur * 256);
#pragma unroll
        for (int reg = 0; reg < 4; ++reg) {
            int rl = l4 * 4 + reg;            // C/D row = (lane>>4)*4+reg
            float lr = llrs[rl];              // broadcast read (16 lanes share)
#pragma unroll
            for (int nfr = 0; nfr < 2; ++nfr) {
                int col = w * 32 + nfr * 16 + l15;  // C/D col = lane&15
                float x = acc[nfr][reg] + fmaf(lr, u_r[nfr], c_r[nfr]);
                float g = 1.0f / (1.0f + __expf(-x));
                int gcol = w * 8 + nfr * 4 + (l15 >> 2);
                float vf = *reinterpret_cast<const float*>(
                    buf + rl * 512 + ((gcol ^ (rl & 7)) << 4) + (l15 & 3) * 4);
                float lf = fmaf(lr, wl_r[nfr], bl_r[nfr]);
                __builtin_nontemporal_store(
                    fmaf(g, lf - vf, vf),
                    &out[(size_t)(rowBase + rl) * H + col]);
            }
        }
        FENCE();
        cur = (cur == 2) ? 0 : cur + 1;
    }
}

extern "C" void kernel_launch(void* const* d_in, const int* in_sizes, int n_in,
                              void* d_out, int out_size, void* d_ws, size_t ws_size,
                              hipStream_t stream) {
    const float* nf     = (const float*)d_in[0];
    const float* llr    = (const float*)d_in[1];
    const float* W_llr  = (const float*)d_in[2];
    const float* b_llr  = (const float*)d_in[3];
    const float* W_gate = (const float*)d_in[4];
    const float* b_gate = (const float*)d_in[5];
    float* out = (float*)d_out;
    float* uc  = (float*)d_ws;  // 512 floats: u, c, W_llr, b_llr

    precompute_uc_kernel<<<1, 128, 0, stream>>>(W_llr, b_llr, W_gate, b_gate, uc);

    // Single change vs R22 (verified 220.3 us): NT cache-policy bit (aux=2)
    // on the global_load_lds stage loads — completes the nt policy across
    // ALL streaming traffic (stage reads were the last 307 MB allocating
    // L2/L3). Partition/schedule byte-identical: 625 compute + 399 copy,
    // grid 1024 = exactly 4 blocks/CU (LDS 32 KB, VGPR <= 128).
    fused_residual_llr_kernel<<<NCOMP + NCOPY, 256, 0, stream>>>(
        nf, llr, W_gate, uc, out);
}

// Round 24
// 218.717 us; speedup vs baseline: 1.0146x; 1.0146x over previous
//
#include <hip/hip_runtime.h>
#include <hip/hip_bf16.h>

// N=1e6 nodes, V=6e5 var nodes, H=128.
constexpr int H = 128;
constexpr int V = 600000;
constexpr int NTOT = 1000000;
constexpr int NT = 60;      // tiles/compute block; 625 x 60 x 16 = 600000 exact
constexpr int NCOMP = 625;  // compute blocks (b < NCOMP)
constexpr int NCOPY = 399;  // copy blocks; 625+399 = 1024 = exactly 4/CU

typedef short bf16x8 __attribute__((ext_vector_type(8)));   // 8 bf16 = 4 VGPR
typedef float f32x4 __attribute__((ext_vector_type(4)));    // clang native vec
typedef unsigned int u32;

__device__ __forceinline__ short f2bf(float f) {  // RNE bf16
    unsigned u = __float_as_uint(f);
    u += 0x7FFF + ((u >> 16) & 1);
    return (short)(u >> 16);
}

// async global->LDS; ldsDst is WAVE-UNIFORM base, lane i lands at dst+i*sz.
__device__ __forceinline__ void async_copy16(char* ldsDst, const float* gSrc) {
    __builtin_amdgcn_global_load_lds(
        (const __attribute__((address_space(1))) u32*)gSrc,
        (__attribute__((address_space(3))) u32*)ldsDst, 16, 0, 0);
}
__device__ __forceinline__ void async_copy4(char* ldsDst, const float* gSrc) {
    __builtin_amdgcn_global_load_lds(
        (const __attribute__((address_space(1))) u32*)gSrc,
        (__attribute__((address_space(3))) u32*)ldsDst, 4, 0, 0);
}
#define FENCE() asm volatile("" ::: "memory")

// uc[h]=u, uc[128+h]=c : logits[i][h] = vf_i . W1[:,h] + llr_i*u[h] + c[h]
// uc[256..383]=W_llr, uc[384..511]=b_llr
__global__ void precompute_uc_kernel(const float* __restrict__ W_llr,
                                     const float* __restrict__ b_llr,
                                     const float* __restrict__ W_gate,
                                     const float* __restrict__ b_gate,
                                     float* __restrict__ uc) {
    int h = threadIdx.x;  // 128 threads
    float u = 0.0f, c = 0.0f;
    for (int k = 0; k < H; ++k) {
        float w2 = W_gate[(size_t)(H + k) * H + h];
        u += W_llr[k] * w2;
        c += b_llr[k] * w2;
    }
    uc[h] = u;
    uc[H + h] = c + b_gate[h];
    uc[2 * H + h] = W_llr[h];
    uc[3 * H + h] = b_llr[h];
}

// LDS 32 KB. Prologue: W1^T bf16 (128 x 256 B, n*256+k*2) -> Bf VGPRs.
// Main loop overlay: 3 A-buffers of 8 KB (16 rows x 512 B fp32) at 0/8K/16K,
// plus 3 llr slots of 256 B at 24576+bi*256.
// A-granule involution (rule 21, round-7-verified): LDS granule g' of row r
// holds global granule g'^(r&7); every read applies the same XOR.
#define LDS_BYTES 32768
#define ABUF 8192
#define LLR_BASE 24576

__global__ __launch_bounds__(256, 4) void fused_residual_llr_kernel(
    const float* __restrict__ nf,      // [N][H]
    const float* __restrict__ llr,     // [V]
    const float* __restrict__ W_gate,  // [2H][H]
    const float* __restrict__ uc,      // [4H]
    float* __restrict__ out) {         // [N][H]
    int b = blockIdx.x;
    int tid = threadIdx.x;

    if (b >= NCOMP) {
        // ---- copy role: rows V..N, 4-deep guarded, NON-TEMPORAL (R22).
        size_t base = (size_t)V * H;
        const f32x4* src = reinterpret_cast<const f32x4*>(nf + base);
        f32x4* dst = reinterpret_cast<f32x4*>(out + base);
        const size_t n4 = ((size_t)(NTOT - V) * H) / 4;  // 12.8M float4
        size_t i0 = (size_t)(b - NCOMP) * 256 + tid;
        const size_t stride = (size_t)NCOPY * 256;       // 102144
#pragma unroll 1
        for (size_t i = i0; i < n4; i += 4 * stride) {
            f32x4 v0, v1, v2, v3;
            bool g1 = i + stride < n4, g2 = i + 2 * stride < n4,
                 g3 = i + 3 * stride < n4;
            v0 = __builtin_nontemporal_load(&src[i]);
            if (g1) v1 = __builtin_nontemporal_load(&src[i + stride]);
            if (g2) v2 = __builtin_nontemporal_load(&src[i + 2 * stride]);
            if (g3) v3 = __builtin_nontemporal_load(&src[i + 3 * stride]);
            __builtin_nontemporal_store(v0, &dst[i]);
            if (g1) __builtin_nontemporal_store(v1, &dst[i + stride]);
            if (g2) __builtin_nontemporal_store(v2, &dst[i + 2 * stride]);
            if (g3) __builtin_nontemporal_store(v3, &dst[i + 3 * stride]);
        }
        return;
    }
    int cb = b;  // compute-block index 0..624; rows [cb*960, cb*960+960)

    __shared__ __align__(16) char lds[LDS_BYTES];

    int lane = tid & 63;
    int w = tid >> 6;          // wave 0..3; wave owns cols [w*32, w*32+32)
    int l15 = lane & 15;
    int l4 = lane >> 4;

    // ---- prologue: stage W1^T bf16 (linear n*256 + k*2) ----
#pragma unroll 4
    for (int j = 0; j < 16; ++j) {  // 4096 float4 of W1
        int idx = tid + 256 * j;
        int k = idx >> 5, c4 = idx & 31;
        f32x4 wv = reinterpret_cast<const f32x4*>(W_gate)[(size_t)k * 32 + c4];
#pragma unroll
        for (int e = 0; e < 4; ++e) {
            int n = c4 * 4 + e;
            *reinterpret_cast<short*>(lds + n * 256 + k * 2) = f2bf(wv[e]);
        }
    }
    float u_r[2], c_r[2], wl_r[2], bl_r[2];
#pragma unroll
    for (int nfr = 0; nfr < 2; ++nfr) {
        int col = w * 32 + nfr * 16 + l15;
        u_r[nfr]  = uc[col];
        c_r[nfr]  = uc[128 + col];
        wl_r[nfr] = uc[256 + col];
        bl_r[nfr] = uc[384 + col];
    }
    __syncthreads();

    // B fragments, held in VGPRs for all tiles
    bf16x8 Bf[4][2];
#pragma unroll
    for (int kk = 0; kk < 4; ++kk)
#pragma unroll
        for (int nfr = 0; nfr < 2; ++nfr) {
            int n = w * 32 + nfr * 16 + l15;
            Bf[kk][nfr] = *reinterpret_cast<const bf16x8*>(
                lds + n * 256 + kk * 64 + l4 * 16);
        }
    __syncthreads();  // full drain: vmcnt=0 baseline; W region reusable

    int rowBase0 = cb * (NT * 16);

    // STAGE(tt,bi): per wave exactly 3 vmem LOADS (2x copy16 A + 1x copy4 llr)
#define STAGE(tt, bi)                                                        \
    {                                                                        \
        char* nbuf_ = lds + (bi) * ABUF;                                     \
        int rb_ = rowBase0 + (tt) * 16;                                      \
        _Pragma("unroll")                                                    \
        for (int j_ = 0; j_ < 2; ++j_) {                                     \
            int seg_ = w * 2 + j_;                                           \
            int rl_ = seg_ * 2 + (lane >> 5);                                \
            int gg_ = (lane & 31) ^ (rl_ & 7);                               \
            async_copy16(nbuf_ + seg_ * 1024,                                \
                         nf + (size_t)(rb_ + rl_) * H + gg_ * 4);            \
        }                                                                    \
        async_copy4(lds + LLR_BASE + (bi) * 256, llr + rb_ + (lane & 15));   \
    }

    STAGE(0, 0);
    FENCE();
    STAGE(1, 1);
    FENCE();

    int cur = 0;  // buffer of tile t
#pragma unroll 1
    for (int t = 0; t < NT; ++t) {
        int rowBase = rowBase0 + t * 16;

        // (C) counted wait for stage(t) ONLY (issue-order FIFO, m135).
        //     Ops newer than stage(t)'s last op at this wait:
        //       t=0:     stage(1)·3                                  ->  3
        //       t=1:     stage(2)·3 + epi(0)·8                       -> 11
        //       2<=t<NT-1: epi(t-2)·8 + stage(t+1)·3 + epi(t-1)·8    -> 19
        //       t=NT-1:  epi·8 + epi·8 (no stage(NT) exists)         -> 16
        if (t == 0)           asm volatile("s_waitcnt vmcnt(3)" ::: "memory");
        else if (t == 1)      asm volatile("s_waitcnt vmcnt(11)" ::: "memory");
        else if (t == NT - 1) asm volatile("s_waitcnt vmcnt(16)" ::: "memory");
        else                  asm volatile("s_waitcnt vmcnt(19)" ::: "memory");
        // (D) raw barrier: all waves' stage(t) visible; all waves are DONE
        //     with tile t-1's buffer (they reached here only after its F).
        __builtin_amdgcn_s_barrier();
        FENCE();

        // (A) stage t+2 into b(t+2)=b(t-1) — safe only AFTER the barrier
        if (t + 2 < NT) {
            int tgt = (cur == 0) ? 2 : cur - 1;  // (cur+2)%3
            STAGE(t + 2, tgt);
        }
        FENCE();

        // (E) MFMA from buf[cur]: fp32 ds_read (swizzled) -> bf16 -> mfma
        char* buf = lds + cur * ABUF;
        f32x4 acc[2];
        acc[0] = (f32x4){0.f, 0.f, 0.f, 0.f};
        acc[1] = (f32x4){0.f, 0.f, 0.f, 0.f};
#pragma unroll
        for (int kk = 0; kk < 4; ++kk) {
            int g0 = (l4 * 2) ^ (l15 & 7);
            const char* base = buf + l15 * 512 + kk * 128;
            f32x4 lo = *reinterpret_cast<const f32x4*>(base + (g0 << 4));
            f32x4 hi = *reinterpret_cast<const f32x4*>(base + ((g0 ^ 1) << 4));
            bf16x8 a;
            a[0] = f2bf(lo[0]); a[1] = f2bf(lo[1]);
            a[2] = f2bf(lo[2]); a[3] = f2bf(lo[3]);
            a[4] = f2bf(hi[0]); a[5] = f2bf(hi[1]);
            a[6] = f2bf(hi[2]); a[7] = f2bf(hi[3]);
            acc[0] = __builtin_amdgcn_mfma_f32_16x16x32_bf16(
                a, Bf[kk][0], acc[0], 0, 0, 0);
            acc[1] = __builtin_amdgcn_mfma_f32_16x16x32_bf16(
                a, Bf[kk][1], acc[1], 0, 0, 0);
        }

        // (F) epilogue: gate, blend with exact fp32 vf from LDS, 8 stores
        //     (NON-TEMPORAL: output is write-once streaming).
        const float* llrs = reinterpret_cast<const float*>(lds + LLR_BASE + cur * 256);
#pragma unroll
        for (int reg = 0; reg < 4; ++reg) {
            int rl = l4 * 4 + reg;            // C/D row = (lane>>4)*4+reg
            float lr = llrs[rl];              // broadcast read (16 lanes share)
#pragma unroll
            for (int nfr = 0; nfr < 2; ++nfr) {
                int col = w * 32 + nfr * 16 + l15;  // C/D col = lane&15
                float x = acc[nfr][reg] + fmaf(lr, u_r[nfr], c_r[nfr]);
                float g = 1.0f / (1.0f + __expf(-x));
                int gcol = w * 8 + nfr * 4 + (l15 >> 2);
                float vf = *reinterpret_cast<const float*>(
                    buf + rl * 512 + ((gcol ^ (rl & 7)) << 4) + (l15 & 3) * 4);
                float lf = fmaf(lr, wl_r[nfr], bl_r[nfr]);
                __builtin_nontemporal_store(
                    fmaf(g, lf - vf, vf),
                    &out[(size_t)(rowBase + rl) * H + col]);
            }
        }
        FENCE();
        cur = (cur == 2) ? 0 : cur + 1;
    }
}

extern "C" void kernel_launch(void* const* d_in, const int* in_sizes, int n_in,
                              void* d_out, int out_size, void* d_ws, size_t ws_size,
                              hipStream_t stream) {
    const float* nf     = (const float*)d_in[0];
    const float* llr    = (const float*)d_in[1];
    const float* W_llr  = (const float*)d_in[2];
    const float* b_llr  = (const float*)d_in[3];
    const float* W_gate = (const float*)d_in[4];
    const float* b_gate = (const float*)d_in[5];
    float* out = (float*)d_out;
    float* uc  = (float*)d_ws;  // 512 floats: u, c, W_llr, b_llr

    precompute_uc_kernel<<<1, 128, 0, stream>>>(W_llr, b_llr, W_gate, b_gate, uc);

    // FINAL (R22 configuration, measured best 220.3 us):
    // - rank-1 algebraic reduction (concat-matmul -> K=128 MFMA + u,c vectors)
    // - bf16 MFMA from XOR-swizzled LDS tiles staged via global_load_lds
    // - depth-2 counted-vmcnt pipeline, stage-after-barrier (race-free)
    // - byte-balanced fused partition: 625 compute + 399 copy = 1024 = 4/CU
    // - non-temporal policy on streaming copy loads/stores + epilogue stores
    fused_residual_llr_kernel<<<NCOMP + NCOPY, 256, 0, stream>>>(
        nf, llr, W_gate, uc, out);
}